// Round 5
// baseline (152.979 us; speedup 1.0000x reference)
//
#include <hip/hip_runtime.h>

// MinibatchDiscrimination, two kernels + memset:
//   memset      : x[i][k*8+d] = 0                        (1.6 MB)
//   K1 proj_at  : x += log2e * (inputs @ T)  split-K 16, unsafeAtomicAdd
//   K2 pairk    : out[i,k] = sum_j exp2(-sum_d |x_i-x_j|)  (1 k per block)
//
// inputs [512,1024] f32, T [1024,500] f32, out [512,100] f32.

#define BB 512
#define FF 1024
#define KK 100
#define KD 500
#define XROW 800           // padded x row: 100 k * 8 floats
#define SPLITS 16
#define FN (FF / SPLITS)   // 64 f per split
#define STEPS (FN / 16)    // 4
#define LOG2E 1.4426950408889634f

// ---------------- K1: register-tiled split-K GEMM, atomic epilogue --------
// grid (8 i-tiles, 8 kd-tiles, 16 splits) = 1024 blocks (4/CU), block 256.
// Tile 64i x 64kd, per-thread 4x4, reg-double-buffered staging.
__global__ __launch_bounds__(256, 4) void proj_at(
    const float* __restrict__ in, const float* __restrict__ T,
    float* __restrict__ x)
{
    const int i0  = blockIdx.x * 64;
    const int kd0 = blockIdx.y * 64;
    const int s   = blockIdx.z;
    const int t   = threadIdx.x;
    const int tk  = t & 15;
    const int ti  = t >> 4;

    __shared__ float Ads[16][68];   // [f][i]
    __shared__ float Bds[16][64];   // [f][kd]

    float acc[4][4];
    #pragma unroll
    for (int r = 0; r < 4; ++r)
        #pragma unroll
        for (int c = 0; c < 4; ++c) acc[r][c] = 0.f;

    const int ia  = t >> 2;                 // i row for A staging
    const int fqa = t & 3;                  // f-quad for A
    const int kb  = t & 63;                 // kd lane for B
    const int frb = t >> 6;                 // f-quad for B
    const int kbc = min(kd0 + kb, KD - 1);

    const float* inb = in + (size_t)(i0 + ia) * FF + s * FN;
    const float* Tb  = T + (size_t)(s * FN) * KD + kbc;

    float4 av = *(const float4*)&inb[fqa * 4];
    float bv0 = Tb[(size_t)(frb * 4 + 0) * KD];
    float bv1 = Tb[(size_t)(frb * 4 + 1) * KD];
    float bv2 = Tb[(size_t)(frb * 4 + 2) * KD];
    float bv3 = Tb[(size_t)(frb * 4 + 3) * KD];

    for (int step = 0; step < STEPS; ++step) {
        Ads[fqa * 4 + 0][ia] = av.x;
        Ads[fqa * 4 + 1][ia] = av.y;
        Ads[fqa * 4 + 2][ia] = av.z;
        Ads[fqa * 4 + 3][ia] = av.w;
        Bds[frb * 4 + 0][kb] = bv0;
        Bds[frb * 4 + 1][kb] = bv1;
        Bds[frb * 4 + 2][kb] = bv2;
        Bds[frb * 4 + 3][kb] = bv3;
        __syncthreads();

        if (step + 1 < STEPS) {     // prefetch next step; hides under FMAs
            const int fo = (step + 1) * 16;
            av  = *(const float4*)&inb[fo + fqa * 4];
            bv0 = Tb[(size_t)(fo + frb * 4 + 0) * KD];
            bv1 = Tb[(size_t)(fo + frb * 4 + 1) * KD];
            bv2 = Tb[(size_t)(fo + frb * 4 + 2) * KD];
            bv3 = Tb[(size_t)(fo + frb * 4 + 3) * KD];
        }

        #pragma unroll
        for (int f = 0; f < 16; ++f) {
            float4 a = *(const float4*)&Ads[f][ti * 4];
            float4 b = *(const float4*)&Bds[f][tk * 4];
            float ar[4] = {a.x, a.y, a.z, a.w};
            float br[4] = {b.x, b.y, b.z, b.w};
            #pragma unroll
            for (int r = 0; r < 4; ++r)
                #pragma unroll
                for (int c = 0; c < 4; ++c)
                    acc[r][c] = fmaf(ar[r], br[c], acc[r][c]);
        }
        if (step + 1 < STEPS) __syncthreads();
    }

    // atomic epilogue into padded layout x[i][k*8+d], pre-scaled by log2e
    #pragma unroll
    for (int r = 0; r < 4; ++r) {
        const int i = i0 + ti * 4 + r;
        #pragma unroll
        for (int c = 0; c < 4; ++c) {
            const int kd = kd0 + tk * 4 + c;
            if (kd < KD) {
                const int k = kd / 5;
                const int d = kd - 5 * k;
                unsafeAtomicAdd(&x[(size_t)i * XROW + k * 8 + d],
                                acc[r][c] * LOG2E);
            }
        }
    }
}

// ---------------- K2: pairwise exp2(-L1), one k per block ----------------
// grid (8 i-tiles, 100 k) = 800 blocks, block 256 (4 waves).
// Wave w: j in [w*128, (w+1)*128). xs reads are uniform -> LDS broadcast.
__global__ __launch_bounds__(256) void pairk(
    const float* __restrict__ x, float* __restrict__ out)
{
    const int i0 = blockIdx.x * 64;
    const int k  = blockIdx.y;
    const int t  = threadIdx.x;
    const int lane = t & 63;
    const int w    = t >> 6;

    __shared__ float xs[BB][8];     // 16 KiB
    __shared__ float ps[4][64];

    // fill: per thread rows t and t+256, aligned float4 + float
    #pragma unroll
    for (int rr = 0; rr < 2; ++rr) {
        const int j = t + rr * 256;
        const float* src = &x[(size_t)j * XROW + k * 8];
        *(float4*)&xs[j][0] = *(const float4*)src;
        xs[j][4] = src[4];
    }
    __syncthreads();

    const int i = i0 + lane;
    const float4 xi0 = *(const float4*)&xs[i][0];
    const float  xi4 = xs[i][4];

    float s0 = 0.f, s1 = 0.f;
    const int j0 = w << 7;
    #pragma unroll 2
    for (int jj = 0; jj < 128; jj += 2) {
        {
            const int j = j0 + jj;
            float4 xj = *(const float4*)&xs[j][0];
            float xj4 = xs[j][4];
            float aa = (fabsf(xi0.x - xj.x) + fabsf(xi0.y - xj.y))
                     + (fabsf(xi0.z - xj.z) + fabsf(xi0.w - xj.w))
                     + fabsf(xi4 - xj4);
            s0 += __builtin_amdgcn_exp2f(-aa);
        }
        {
            const int j = j0 + jj + 1;
            float4 xj = *(const float4*)&xs[j][0];
            float xj4 = xs[j][4];
            float aa = (fabsf(xi0.x - xj.x) + fabsf(xi0.y - xj.y))
                     + (fabsf(xi0.z - xj.z) + fabsf(xi0.w - xj.w))
                     + fabsf(xi4 - xj4);
            s1 += __builtin_amdgcn_exp2f(-aa);
        }
    }

    ps[w][lane] = s0 + s1;
    __syncthreads();

    if (t < 64)
        out[(size_t)(i0 + t) * KK + k] =
            (ps[0][t] + ps[1][t]) + (ps[2][t] + ps[3][t]);
}

// ---------------- Fallback (ws too small): round-1 fused ----------------
__global__ __launch_bounds__(1024, 1) void mbd_fused(
    const float* __restrict__ in, const float* __restrict__ T, float* __restrict__ out)
{
    const int k = blockIdx.x;
    const int t = threadIdx.x;
    const int i = t & (BB - 1);
    const int h = t >> 9;

    __shared__ float xk[1024][8];

    float a0 = 0.f, a1 = 0.f, a2 = 0.f, a3 = 0.f, a4 = 0.f;
    const float4* inrow = (const float4*)(in + (size_t)i * FF + (size_t)h * 512);
    const float* Tk = T + 5 * k + (size_t)h * 512 * KD;

    for (int ff = 0; ff < 512; ff += 4) {
        float4 v = inrow[ff >> 2];
        const float* tp = Tk + (size_t)ff * KD;
        a0 = fmaf(v.x, tp[0], a0); a1 = fmaf(v.x, tp[1], a1); a2 = fmaf(v.x, tp[2], a2);
        a3 = fmaf(v.x, tp[3], a3); a4 = fmaf(v.x, tp[4], a4); tp += KD;
        a0 = fmaf(v.y, tp[0], a0); a1 = fmaf(v.y, tp[1], a1); a2 = fmaf(v.y, tp[2], a2);
        a3 = fmaf(v.y, tp[3], a3); a4 = fmaf(v.y, tp[4], a4); tp += KD;
        a0 = fmaf(v.z, tp[0], a0); a1 = fmaf(v.z, tp[1], a1); a2 = fmaf(v.z, tp[2], a2);
        a3 = fmaf(v.z, tp[3], a3); a4 = fmaf(v.z, tp[4], a4); tp += KD;
        a0 = fmaf(v.w, tp[0], a0); a1 = fmaf(v.w, tp[1], a1); a2 = fmaf(v.w, tp[2], a2);
        a3 = fmaf(v.w, tp[3], a3); a4 = fmaf(v.w, tp[4], a4);
    }
    xk[t][0] = a0; xk[t][1] = a1; xk[t][2] = a2; xk[t][3] = a3; xk[t][4] = a4;
    __syncthreads();
    if (t < BB) {
        xk[t][0] += xk[t + BB][0]; xk[t][1] += xk[t + BB][1]; xk[t][2] += xk[t + BB][2];
        xk[t][3] += xk[t + BB][3]; xk[t][4] += xk[t + BB][4];
    }
    __syncthreads();

    const int jg = t >> 9;
    const float4 xiv = *(const float4*)&xk[i][0];
    const float xi4 = xk[i][4];
    const float NEG_LOG2E = -1.4426950408889634f;
    float s0 = 0.f;
    const int j0 = jg << 8;
    for (int jj = 0; jj < 256; ++jj) {
        const int j = j0 + jj;
        float4 xj = *(const float4*)&xk[j][0];
        float xj4 = xk[j][4];
        float aa = (fabsf(xiv.x - xj.x) + fabsf(xiv.y - xj.y))
                 + (fabsf(xiv.z - xj.z) + fabsf(xiv.w - xj.w)) + fabsf(xi4 - xj4);
        s0 += __builtin_amdgcn_exp2f(NEG_LOG2E * aa);
    }
    xk[BB + i][jg] = s0;
    __syncthreads();
    if (t < BB)
        out[(size_t)t * KK + k] = xk[BB + t][0] + xk[BB + t][1];
}

// ---------------- launch ----------------
extern "C" void kernel_launch(void* const* d_in, const int* in_sizes, int n_in,
                              void* d_out, int out_size, void* d_ws, size_t ws_size,
                              hipStream_t stream) {
    const float* in = (const float*)d_in[0];   // [512, 1024]
    const float* T  = (const float*)d_in[1];   // [1024, 500]
    float* out = (float*)d_out;                // [512, 100]

    const size_t x_bytes = (size_t)BB * XROW * sizeof(float);   // 1.6 MB

    if (ws_size < x_bytes) {
        mbd_fused<<<KK, 1024, 0, stream>>>(in, T, out);
        return;
    }

    float* x = (float*)d_ws;
    hipMemsetAsync(x, 0, x_bytes, stream);

    dim3 g1(BB / 64, 8, SPLITS);       // 8 x 8 x 16 = 1024 blocks
    proj_at<<<g1, 256, 0, stream>>>(in, T, x);

    dim3 g2(BB / 64, KK);              // 8 x 100 = 800 blocks
    pairk<<<g2, 256, 0, stream>>>(x, out);
}